// Round 1
// 326.220 us; speedup vs baseline: 1.0450x; 1.0450x over previous
//
#include <hip/hip_runtime.h>
#include <hip/hip_fp16.h>
#include <cmath>

// ---------------------------------------------------------------------------
// Self_Attention: B=8, C=256, C_=32, H=W=64, N=4096, GAMMA=1.0
// R5 = R4 with pass2 restructured: each block now owns the FULL C=256
// (4 waves x 64c, ns=4) instead of two c-split blocks (ns=2).
//   - LDS A-frag b128 reads per O-MFMA halved (1:4 instead of 1:2)
//   - S-tile + exp/P chain computed once per (i0,j) instead of twice
//   - per-wave step = 4 S-MFMA + 32 O-MFMA (long ILP stretch per barrier)
// grid 1024 -> 512, launch_bounds(256,2) (VGPR ~185, 2 waves/SIMD).
// cvtw folded into transpose (tail blocks) - one fewer launch.
// ws: xt 16M | wf 256K | ft 2M | gt 2M | hm 16M | linv 128K
// ---------------------------------------------------------------------------

#define BN 8
#define CC 256
#define CQ 32
#define NN 4096

typedef _Float16 half8 __attribute__((ext_vector_type(8)));
typedef _Float16 half4v __attribute__((ext_vector_type(4)));
typedef float f32x4 __attribute__((ext_vector_type(4)));

static __device__ __forceinline__ float fexp2(float x) {
    return __builtin_amdgcn_exp2f(x);
}

#define LOG2E 1.44269504f
#define SHIFT2 28.8539008f   /* 20 * log2(e) */

// --------------------------------------------------------------------------
// K1: transpose + cvt x[b][c][n] f32 -> xt[b][n][c] f16.  64n x 64c tiles.
// Tail blocks (gid >= 2048) do the weight f32->f16 conversion (fused cvtw).
// grid 2368: first 2048 transpose (b = gid&7 XCD affinity), last 320 weights.
// --------------------------------------------------------------------------
__global__ __launch_bounds__(256) void transpose_kernel(
    const float* __restrict__ x, __half* __restrict__ xt,
    const float* __restrict__ fw, const float* __restrict__ gw,
    const float* __restrict__ hw, __half* __restrict__ wf16)
{
    const int gid = blockIdx.x;

    if (gid >= 2048) {
        // fused weight conversion: 8192 + 8192 + 65536 = 81920 elements
        int i = (gid - 2048) * 256 + threadIdx.x;
        float v;
        if (i < 8192)       v = fw[i];
        else if (i < 16384) v = gw[i - 8192];
        else                v = hw[i - 16384];
        wf16[i] = __float2half(v);
        return;
    }

    const int b = gid & 7, rest = gid >> 3;
    const int n0 = (rest & 63) * 64;
    const int c0 = (rest >> 6) * 64;
    const int tid = threadIdx.x;

    __shared__ float T[64 * 65];

    const float* xb = x + ((size_t)b * CC + c0) * NN + n0;
    const int u  = tid >> 4;          // 0..15
    const int n4 = (tid & 15) * 4;
#pragma unroll
    for (int r = 0; r < 4; ++r) {
        int c = r * 16 + u;
        f32x4 v = __builtin_nontemporal_load((const f32x4*)(xb + (size_t)c * NN + n4));
        T[c * 65 + n4 + 0] = v.x;
        T[c * 65 + n4 + 1] = v.y;
        T[c * 65 + n4 + 2] = v.z;
        T[c * 65 + n4 + 3] = v.w;
    }
    __syncthreads();

    const int lane = tid & 63, w = tid >> 6;
    const int n  = w * 16 + (lane >> 2);
    const int cc = (lane & 3) * 16;
    half8 o0, o1;
#pragma unroll
    for (int k = 0; k < 8; ++k) {
        o0[k] = (_Float16)T[(cc + k) * 65 + n];
        o1[k] = (_Float16)T[(cc + 8 + k) * 65 + n];
    }
    __half* dst = xt + ((size_t)b * NN + n0 + n) * CC + c0 + cc;
    *(half8*)(void*)dst = o0;
    *(half8*)(void*)(dst + 8) = o1;
}

// --------------------------------------------------------------------------
// K2: MFMA projections. 1D grid 2560: b = gid&7, then (nt 0..63, ot 0..4).
//   ot==0: f+g.  A=W (m=c_out), B=xt (n=pix) -> ft/gt[n][32] b64 stores.
//   ot>=1: h.    A=xt (m=pix), B=Wh (n=c_out) -> hm[c][n] b64 stores.
// --------------------------------------------------------------------------
__global__ __launch_bounds__(256) void proj_kernel(
    const __half* __restrict__ xt, const __half* __restrict__ wf16,
    const float* __restrict__ fb, const float* __restrict__ gb,
    const float* __restrict__ hb,
    __half* __restrict__ ft, __half* __restrict__ gt, __half* __restrict__ hm)
{
    const int tid = threadIdx.x;
    const int w = tid >> 6, lane = tid & 63, col = lane & 15, q = lane >> 4;
    const int gid = blockIdx.x;
    const int b = gid & 7, rest = gid >> 3;
    const int n0 = (rest & 63) * 64;
    const int ot = rest >> 6;          // 0..4

    const __half* xtb  = xt + (size_t)b * NN * CC;
    const __half* fw16 = wf16;
    const __half* gw16 = wf16 + 8192;
    const __half* hw16 = wf16 + 16384;

    f32x4 acc[4];
#pragma unroll
    for (int mt = 0; mt < 4; ++mt) acc[mt] = (f32x4){0.f, 0.f, 0.f, 0.f};

    if (ot == 0) {
        const int pix = n0 + 16 * w + col;
#pragma unroll
        for (int ks = 0; ks < 8; ++ks) {
            half8 bf = *(const half8*)(const void*)(xtb + (size_t)pix * CC + ks * 32 + q * 8);
#pragma unroll
            for (int mt = 0; mt < 4; ++mt) {
                const __half* wp = (mt < 2) ? (fw16 + (16 * mt + col) * CC)
                                            : (gw16 + (16 * (mt - 2) + col) * CC);
                half8 af = *(const half8*)(const void*)(wp + ks * 32 + q * 8);
                acc[mt] = __builtin_amdgcn_mfma_f32_16x16x32_f16(af, bf, acc[mt], 0, 0, 0);
            }
        }
#pragma unroll
        for (int mt = 0; mt < 4; ++mt) {
            const int mtl = mt & 1;
            const float* bsel = (mt < 2) ? fb : gb;
            __half* dsel = (mt < 2) ? ft : gt;
            half4v hv;
#pragma unroll
            for (int r = 0; r < 4; ++r)
                hv[r] = (_Float16)(acc[mt][r] + bsel[16 * mtl + 4 * q + r]);
            *(half4v*)(void*)(dsel + ((size_t)b * NN + pix) * CQ + 16 * mtl + 4 * q) = hv;
        }
    } else {
        const int c = (ot - 1) * 64 + 16 * w + col;
#pragma unroll
        for (int ks = 0; ks < 8; ++ks) {
            half8 bf = *(const half8*)(const void*)(hw16 + (size_t)c * CC + ks * 32 + q * 8);
#pragma unroll
            for (int mt = 0; mt < 4; ++mt) {
                half8 af = *(const half8*)(const void*)(xtb + (size_t)(n0 + 16 * mt + col) * CC + ks * 32 + q * 8);
                acc[mt] = __builtin_amdgcn_mfma_f32_16x16x32_f16(af, bf, acc[mt], 0, 0, 0);
            }
        }
        const float bias = hb[c];
#pragma unroll
        for (int mt = 0; mt < 4; ++mt) {
            half4v hv;
#pragma unroll
            for (int r = 0; r < 4; ++r)
                hv[r] = (_Float16)(acc[mt][r] + bias);
            *(half4v*)(void*)(hm + ((size_t)b * CC + c) * NN + n0 + 16 * mt + 4 * q) = hv;
        }
    }
}

// --------------------------------------------------------------------------
// K3: per-column softmax denominator with constant shift (no max tracking):
// linv[b][j] = 1 / sum_i exp(S_ij - 20).  4 independent f32 accumulators
// (no serial m/l chain), one-step afrag prefetch. 1D grid 512: b = gid&7.
// --------------------------------------------------------------------------
__global__ __launch_bounds__(256) void pass1_kernel(
    const __half* __restrict__ ft, const __half* __restrict__ gt,
    float* __restrict__ linv)
{
    const int tid = threadIdx.x;
    const int w = tid >> 6, lane = tid & 63, col = lane & 15, q = lane >> 4;
    const int gid = blockIdx.x;
    const int b = gid & 7;
    const int jg = (gid >> 3) * 64 + 16 * w + col;

    const __half* fbase = ft + (size_t)b * NN * CQ;
    half8 gfrag = *(const half8*)(const void*)(gt + ((size_t)b * NN + jg) * CQ + q * 8);

    float a0 = 0.f, a1 = 0.f, a2 = 0.f, a3 = 0.f;
    const f32x4 zero = {0.f, 0.f, 0.f, 0.f};

    half8 a_cur = *(const half8*)(const void*)(fbase + (size_t)col * CQ + q * 8);
    for (int i0 = 0; i0 < NN; i0 += 16) {
        int i_n = (i0 + 16) & (NN - 1);
        half8 a_next = *(const half8*)(const void*)(fbase + (size_t)(i_n + col) * CQ + q * 8);
        f32x4 d = __builtin_amdgcn_mfma_f32_16x16x32_f16(a_cur, gfrag, zero, 0, 0, 0);
        a0 += fexp2(fmaf(d[0], LOG2E, -SHIFT2));
        a1 += fexp2(fmaf(d[1], LOG2E, -SHIFT2));
        a2 += fexp2(fmaf(d[2], LOG2E, -SHIFT2));
        a3 += fexp2(fmaf(d[3], LOG2E, -SHIFT2));
        a_cur = a_next;
    }
    float l = (a0 + a1) + (a2 + a3);
    l += __shfl_xor(l, 16);
    l += __shfl_xor(l, 32);
    if (q == 0)
        linv[(size_t)b * NN + jg] = 1.f / l;
}

// --------------------------------------------------------------------------
// K4: O = h @ P^T + x.  Block: 64 i x 256 c (4 waves x 64c), j-step 64.
// 1D grid 512: b = gid&7 -> hm_b (2MB) + gt_b (256KB) resident in XCD-b L2.
// Each block owns the FULL C=256: the shared P tile (S + exp + linv) is
// computed ONCE per (i0, j) and each b128 A-frag read feeds 4 O-MFMAs
// (ns=4).  P tile XOR-swizzled: addr = i*64 + (joff ^ 8*(i&7)) -> b64
// writes and b128 reads both at the bank floor.
// g/linv prefetched one step ahead; hv loaded at step top (latency covered
// by S-MFMA + exp + barrier).  x/out accessed nontemporally (keep L2 for hm).
// --------------------------------------------------------------------------
__global__ __launch_bounds__(256, 2) void pass2_kernel(
    const float* __restrict__ x,
    const __half* __restrict__ ft, const __half* __restrict__ gt,
    const __half* __restrict__ hm, const float* __restrict__ linv,
    float* __restrict__ out)
{
    const int tid = threadIdx.x;
    const int w = tid >> 6, lane = tid & 63, col = lane & 15, q = lane >> 4;
    const int gid = blockIdx.x;
    const int b  = gid & 7;
    const int i0 = (gid >> 3) * 64;          // 64 i-tiles per batch
    const int cb = 64 * w;                   // wave c-slice: 64 channels

    __shared__ __half P[2][64 * 64];

    const __half* gbase = gt + (size_t)b * NN * CQ;
    const __half* hbase = hm + (size_t)b * CC * NN;
    const float*  lb    = linv + (size_t)b * NN;

    // loop-invariant f B-frags (n = i)
    half8 ffr[4];
#pragma unroll
    for (int it = 0; it < 4; ++it)
        ffr[it] = *(const half8*)(const void*)(ft + ((size_t)b * NN + i0 + 16 * it + col) * CQ + q * 8);

    f32x4 acc[4][4];
#pragma unroll
    for (int ms = 0; ms < 4; ++ms)
#pragma unroll
        for (int ns = 0; ns < 4; ++ns)
            acc[ms][ns] = (f32x4){0.f, 0.f, 0.f, 0.f};

    const f32x4 zero = {0.f, 0.f, 0.f, 0.f};
    const int jml = 16 * w + 4 * q;          // this lane's j offset in the step
    const int sw  = 8 * (col & 7);           // P swizzle for this lane's rows

    // prologue prefetch (step 0)
    half8  gfr = *(const half8*)(const void*)(gbase + (size_t)(16 * w + col) * CQ + q * 8);
    float4 il  = *(const float4*)(lb + jml);

    int buf = 0;
    for (int j0 = 0; j0 < NN; j0 += 64, buf ^= 1) {
        // current-step O-phase B-frags (L2-resident hm), ns=4 x ks=2
        half8 hv[4][2];
#pragma unroll
        for (int ns = 0; ns < 4; ++ns)
#pragma unroll
            for (int ks = 0; ks < 2; ++ks)
                hv[ns][ks] = *(const half8*)(const void*)(
                    hbase + (size_t)(cb + 16 * ns + col) * NN + j0 + ks * 32 + q * 8);

        // S^T tiles: rows j = j0+16w+4q+r, cols i = 16it+col
        f32x4 d[4];
#pragma unroll
        for (int it = 0; it < 4; ++it)
            d[it] = __builtin_amdgcn_mfma_f32_16x16x32_f16(gfr, ffr[it], zero, 0, 0, 0);

        // next-step prefetch (wraps harmlessly on last iter)
        const int jn = (j0 + 64) & (NN - 1);
        half8  gfr_n = *(const half8*)(const void*)(gbase + (size_t)(jn + 16 * w + col) * CQ + q * 8);
        float4 il_n  = *(const float4*)(lb + jn + jml);

        // P = exp2(S*log2e - 20*log2e) * linv  -> swizzled LDS
        __half* Pb = &P[buf][0];
#pragma unroll
        for (int it = 0; it < 4; ++it) {
            half4v pv;
            pv[0] = (_Float16)(fexp2(fmaf(d[it][0], LOG2E, -SHIFT2)) * il.x);
            pv[1] = (_Float16)(fexp2(fmaf(d[it][1], LOG2E, -SHIFT2)) * il.y);
            pv[2] = (_Float16)(fexp2(fmaf(d[it][2], LOG2E, -SHIFT2)) * il.z);
            pv[3] = (_Float16)(fexp2(fmaf(d[it][3], LOG2E, -SHIFT2)) * il.w);
            *(half4v*)(void*)(Pb + (16 * it + col) * 64 + (jml ^ sw)) = pv;
        }
        __syncthreads();

        // O: A = P (swizzled b128 reads, each feeds 4 MFMAs), B = hv
#pragma unroll
        for (int ks = 0; ks < 2; ++ks) {
            half8 af[4];
#pragma unroll
            for (int ms = 0; ms < 4; ++ms)
                af[ms] = *(const half8*)(const void*)(
                    Pb + (16 * ms + col) * 64 + ((ks * 32 + q * 8) ^ sw));
#pragma unroll
            for (int ms = 0; ms < 4; ++ms)
#pragma unroll
                for (int ns = 0; ns < 4; ++ns)
                    acc[ms][ns] = __builtin_amdgcn_mfma_f32_16x16x32_f16(
                        af[ms], hv[ns][ks], acc[ms][ns], 0, 0, 0);
        }
        gfr = gfr_n;
        il  = il_n;
    }

    // epilogue: out = O + x (nontemporal both ways; GAMMA = 1)
    const float* xb = x + (size_t)b * CC * NN;
    float* ob = out + (size_t)b * CC * NN;
#pragma unroll
    for (int ms = 0; ms < 4; ++ms) {
#pragma unroll
        for (int ns = 0; ns < 4; ++ns) {
            int c  = cb + 16 * ns + col;
            int ii = i0 + 16 * ms + 4 * q;
            size_t off = (size_t)c * NN + ii;
            f32x4 xv = __builtin_nontemporal_load((const f32x4*)(xb + off));
            f32x4 ov;
            ov.x = acc[ms][ns][0] + xv.x;
            ov.y = acc[ms][ns][1] + xv.y;
            ov.z = acc[ms][ns][2] + xv.z;
            ov.w = acc[ms][ns][3] + xv.w;
            __builtin_nontemporal_store(ov, (f32x4*)(ob + off));
        }
    }
}

// ---------------------------------------------------------------------------
extern "C" void kernel_launch(void* const* d_in, const int* in_sizes, int n_in,
                              void* d_out, int out_size, void* d_ws, size_t ws_size,
                              hipStream_t stream)
{
    const float* x  = (const float*)d_in[0];
    const float* fw = (const float*)d_in[1];
    const float* fb = (const float*)d_in[2];
    const float* gw = (const float*)d_in[3];
    const float* gb = (const float*)d_in[4];
    const float* hw = (const float*)d_in[5];
    const float* hb = (const float*)d_in[6];
    float* out = (float*)d_out;

    char* ws = (char*)d_ws;
    __half* xt = (__half*)(ws);                          // 16,777,216
    __half* wf = (__half*)(ws + (size_t)16777216);       //    163,840 (pad 256K)
    __half* ft = (__half*)(ws + (size_t)17039360);       //  2,097,152
    __half* gt = (__half*)(ws + (size_t)19136512);       //  2,097,152
    __half* hm = (__half*)(ws + (size_t)21233664);       // 16,777,216
    float*  lv = (float*) (ws + (size_t)38010880);       //    131,072

    transpose_kernel<<<dim3(2368), dim3(256), 0, stream>>>(x, xt, fw, gw, hw, wf);
    proj_kernel<<<dim3(2560), dim3(256), 0, stream>>>(xt, wf, fb, gb, hb, ft, gt, hm);
    pass1_kernel<<<dim3(512), dim3(256), 0, stream>>>(ft, gt, lv);
    pass2_kernel<<<dim3(512), dim3(256), 0, stream>>>(x, ft, gt, hm, lv, out);
}